// Round 6
// baseline (167.672 us; speedup 1.0000x reference)
//
#include <hip/hip_runtime.h>
#include <math.h>

typedef float v4f __attribute__((ext_vector_type(4)));

// ---------------- geometry ----------------
#define SD 64
#define CC 64
#define EE 320
#define NS 27
#define NPAIR 351

#define NCHUNK 54
#define AGG_BLKS (27 * NCHUNK)   // 1458

// ws layout (floats)
#define WS_QKV   0                       // 27*960 = 25920
#define WS_ENT   25920                   // 351*64 = 22464 -> 48384
#define WS_MIDP  48384                   // 1458*2*400 = 1166400 -> 1214784
#define WS_CF    1214784                 // 10800 -> 1225584
#define WS_ROOTP 1225584                 // 216*400 = 86400 -> 1311984
#define WS_HPM   1311984                 // 27*4*64 = 6912 -> 1318896
#define WS_HPR   1318896                 // 256 -> 1319152
#define WS_CTR   1319168                 // 32 ints
// ctr indices: [0..26] per-node mid, [27] cf-done, [28] rootagg-done, [29] rootW1-done

__device__ __forceinline__ void spin_wait(int* ctr, int target) {
    if (threadIdx.x == 0) {
        while (__hip_atomic_load(ctr, __ATOMIC_ACQUIRE, __HIP_MEMORY_SCOPE_AGENT) < target)
            __builtin_amdgcn_s_sleep(8);
    }
    __syncthreads();
}

// ================= K1 (256 threads): mid_agg | granger | qkv | ent =================

__device__ void dev_mid_agg(int blk, const float* __restrict__ W,
                            const float* __restrict__ leaf, float* __restrict__ partial) {
    __shared__ float c_l[200];
    int n = blk / NCHUNK, chunk = blk % NCHUNK;
    int t = threadIdx.x;
    if (t < 200) c_l[t] = leaf[n * 10800 + chunk * 200 + t];
    __syncthreads();
    if (t < 200) {
        int rp = t / 100, j4 = t % 100;
        const v4f* Wr = (const v4f*)(W + (size_t)(n * 10800 + chunk * 200) * 400);
        v4f acc = (v4f)(0.0f);
        #pragma unroll 16
        for (int rr = 0; rr < 100; ++rr) {
            int r = 2 * rr + rp;
            v4f w = __builtin_nontemporal_load(&Wr[(size_t)r * 100 + j4]);
            acc += c_l[r] * w;
        }
        ((v4f*)(partial + (size_t)(blk * 2 + rp) * 400))[j4] = acc;
    }
}

__device__ void dev_granger(int blk, const float* __restrict__ x, const float* __restrict__ h,
                            const float* __restrict__ gW, const float* __restrict__ gb,
                            float* __restrict__ out) {
    int idx = blk * 256 + threadIdx.x;
    if (idx >= NS * NS) return;
    int i = idx / NS, j = idx % NS;
    const float* hr = h + j * 320;
    const float* xr = x + i * 320;
    float acc = gb[0];
    for (int k = 0; k < 320; ++k) acc += hr[k] * gW[k] + xr[k] * gW[320 + k];
    float sig = 1.0f / (1.0f + expf(-acc));
    out[idx] = (i == j) ? 0.0f : sig;
}

__device__ void dev_qkv(int blk, const float* __restrict__ x, const float* __restrict__ W,
                        const float* __restrict__ b, float* __restrict__ qkv) {
    int idx = blk * 256 + threadIdx.x;
    if (idx >= NS * 960) return;
    int i = idx / 960, c = idx % 960;
    const float4* xr = (const float4*)(x + i * 320);
    const float4* wr = (const float4*)(W + (size_t)c * 320);
    float acc = b[c];
    #pragma unroll 8
    for (int k = 0; k < 80; ++k) {
        float4 a = xr[k], w = wr[k];
        acc += a.x * w.x + a.y * w.y + a.z * w.z + a.w * w.w;
    }
    qkv[idx] = acc;
}

__device__ void dev_ent(int blk, const float* __restrict__ q_real,
                        const float* __restrict__ W1, const float* __restrict__ b1,
                        const float* __restrict__ W2, const float* __restrict__ b2,
                        float* __restrict__ ent_scaled) {
    __shared__ float comb[2][128];
    __shared__ float hid[2][64];
    int t = threadIdx.x;
    int sub = t >> 7, lt = t & 127;
    int p = blk * 2 + sub;
    bool pv = (p < NPAIR);
    bool valid = pv && (lt < 64);
    int i = 0, jj = 0;
    if (pv) {
        int rem = p;
        while (rem >= 26 - i) { rem -= 26 - i; ++i; }
        jj = i + 1 + rem;
    }
    float qa = 0.f, qb = 0.f;
    if (valid) { qa = q_real[i * CC + lt]; qb = q_real[jj * CC + lt]; }
    float sa = qa, sb = qb;
    #pragma unroll
    for (int off = 32; off; off >>= 1) { sa += __shfl_xor(sa, off); sb += __shfl_xor(sb, off); }
    float coupling = expf(-fabsf(sa - sb) / (500.0f + 1e-6f));
    if (valid) { comb[sub][lt] = qa; comb[sub][64 + lt] = qb; }
    __syncthreads();
    if (valid) {
        float hs = b1[lt];
        for (int ii = 0; ii < 128; ++ii) hs += comb[sub][ii] * W1[ii * 64 + lt];
        hid[sub][lt] = fmaxf(hs, 0.0f);
    }
    __syncthreads();
    if (valid) {
        float e = b2[lt];
        for (int k = 0; k < 64; ++k) e += hid[sub][k] * W2[k * 64 + lt];
        ent_scaled[p * 64 + lt] = e * coupling;
    }
}

__global__ __launch_bounds__(256) void k_stage1(
    const float* __restrict__ mid_agg_W, const float* __restrict__ leaf,
    const float* __restrict__ node, const float* __restrict__ hist,
    const float* __restrict__ gW, const float* __restrict__ gb,
    const float* __restrict__ mha_in_W, const float* __restrict__ mha_in_b,
    const float* __restrict__ q_real,
    const float* __restrict__ ent_W1, const float* __restrict__ ent_b1,
    const float* __restrict__ ent_W2, const float* __restrict__ ent_b2,
    float* __restrict__ mid_partial, float* __restrict__ out_causal,
    float* __restrict__ qkv, float* __restrict__ ent_scaled,
    int* __restrict__ ctrs) {
    int blk = blockIdx.x;
    // zero tail counters using idle lanes of block 0 (K2 sees them after kernel boundary)
    if (blk == 0 && threadIdx.x >= 224) ctrs[threadIdx.x - 224] = 0;
    if (blk < AGG_BLKS)            dev_mid_agg(blk, mid_agg_W, leaf, mid_partial);
    else if (blk < AGG_BLKS + 3)   dev_granger(blk - AGG_BLKS, node, hist, gW, gb, out_causal);
    else if (blk < AGG_BLKS + 105) dev_qkv(blk - AGG_BLKS - 3, node, mha_in_W, mha_in_b, qkv);
    else                           dev_ent(blk - AGG_BLKS - 105, q_real, ent_W1, ent_b1, ent_W2, ent_b2, ent_scaled);
}

// ================= K2 (256 threads): fused tail =================
// blocks: [0,27) attn+proj, [27,61) measured(+local avg), [61,169) mid_up quarters,
//         [169,277) root_agg chunks, [277,281) root W1 quarters

__device__ void dev_attnproj(int q, const float* __restrict__ qkv,
                             const float* __restrict__ Wout, const float* __restrict__ bout,
                             float* __restrict__ out_att) {
    __shared__ float sc[4][27];
    __shared__ float at[4][27];
    __shared__ __align__(16) float o_l[320];
    int t = threadIdx.x;
    if (t < 108) {
        int h = t / 27, k = t % 27;
        const float* qr = qkv + q * 960 + h * 80;
        const float* kr = qkv + k * 960 + 320 + h * 80;
        float s = 0.0f;
        #pragma unroll 8
        for (int d = 0; d < 80; ++d) s += qr[d] * kr[d];
        sc[h][k] = s * 0.1118033988749895f;
    }
    __syncthreads();
    if (t < 4) {
        float m = -1e30f;
        for (int k = 0; k < 27; ++k) m = fmaxf(m, sc[t][k]);
        float sum = 0.0f;
        for (int k = 0; k < 27; ++k) sum += expf(sc[t][k] - m);
        float inv = 1.0f / sum;
        for (int k = 0; k < 27; ++k) at[t][k] = expf(sc[t][k] - m) * inv;
    }
    __syncthreads();
    for (int j = t; j < 320; j += 256) {        // 256-thread block: stride loop over 320
        int h = j / 80;
        float acc = 0.0f;
        for (int k = 0; k < 27; ++k) acc += at[h][k] * qkv[k * 960 + 640 + j];
        o_l[j] = acc;
    }
    __syncthreads();
    for (int j = t; j < 320; j += 256) {        // stride loop over 320 outputs
        const float4* wr = (const float4*)(Wout + (size_t)j * 320);
        const float4* ol = (const float4*)o_l;
        float acc = bout[j];
        #pragma unroll 8
        for (int k = 0; k < 80; ++k) {
            float4 w = wr[k], a = ol[k];
            acc += a.x * w.x + a.y * w.y + a.z * w.z + a.w * w.w;
        }
        out_att[q * 320 + j] = 0.5f * acc;
    }
}

__device__ void dev_measured(int blk, const float* __restrict__ ent_scaled,
                             const float* __restrict__ q_real, const float* __restrict__ q_imag,
                             const float* __restrict__ W, const float* __restrict__ b,
                             float* __restrict__ out) {
    __shared__ float aac[4][64];
    __shared__ float avg_l[64];
    int t = threadIdx.x;
    int col = t & 63, g = t >> 6;
    float s = 0.0f;
    for (int p = g; p < NPAIR; p += 4) s += ent_scaled[p * 64 + col];
    aac[g][col] = s;
    __syncthreads();
    if (t < 64) avg_l[t] = (aac[0][t] + aac[1][t] + aac[2][t] + aac[3][t]) / (float)NPAIR;
    __syncthreads();
    int idx = blk * 256 + t;
    if (idx < NS * EE) {
        int i = idx / EE, c = idx % EE;
        float acc = b[c];
        #pragma unroll 8
        for (int k = 0; k < 64; ++k) {
            float a = avg_l[k];
            acc += (q_real[i * 64 + k] + a) * W[k * EE + c];
            acc += (q_imag[i * 64 + k] + a) * W[(64 + k) * EE + c];
        }
        out[idx] = acc;
    }
}

__device__ void dev_mid_up(int rel, const float* __restrict__ partial, const float* __restrict__ agg_b,
                           const float* __restrict__ mid_states,
                           const float* __restrict__ W1, const float* __restrict__ b1,
                           const float* __restrict__ W2, const float* __restrict__ b2,
                           float* __restrict__ cf, float* __restrict__ hpm, int* __restrict__ ctrs) {
    int n = rel >> 2, p = rel & 3;
    __shared__ float combq[200];
    __shared__ float hp4[4][64];
    __shared__ float hid[64];
    __shared__ int flag;
    int t = threadIdx.x;
    if (p < 2) {
        if (t < 200) combq[t] = mid_states[n * 400 + p * 200 + t];
    } else {
        int j0 = (p - 2) * 200;
        if (t < 200) {
            float a = agg_b[n * 400 + j0 + t];
            const float* pp = partial + (size_t)(n * 108) * 400 + j0 + t;
            #pragma unroll 12
            for (int s = 0; s < 108; ++s) a += pp[s * 400];
            combq[t] = a;
        }
    }
    __syncthreads();
    {
        int h = t & 63, g = t >> 6;   // 4 groups of 50 rows
        const float* w1 = W1 + (size_t)n * 51200 + (size_t)(p * 200) * 64;
        float hs = 0.0f;
        #pragma unroll 5
        for (int i = g * 50; i < g * 50 + 50; ++i) hs += combq[i] * w1[i * 64 + h];
        hp4[g][h] = hs;
    }
    __syncthreads();
    if (t < 64) hpm[(n * 4 + p) * 64 + t] = hp4[0][t] + hp4[1][t] + hp4[2][t] + hp4[3][t];
    __syncthreads();
    if (t == 0) {
        int old = __hip_atomic_fetch_add(&ctrs[n], 1, __ATOMIC_ACQ_REL, __HIP_MEMORY_SCOPE_AGENT);
        flag = (old == 3);
    }
    __syncthreads();
    if (flag) {
        if (t < 64) {
            float hs = b1[n * 64 + t];
            #pragma unroll
            for (int pq = 0; pq < 4; ++pq) hs += hpm[(n * 4 + pq) * 64 + t];
            hid[t] = fmaxf(hs, 0.0f);
        }
        __syncthreads();
        const float* w2 = W2 + (size_t)n * 25600;
        for (int j = t; j < 400; j += 256) {
            float u = b2[n * 400 + j];
            #pragma unroll 8
            for (int k = 0; k < 64; ++k) u += hid[k] * w2[k * 400 + j];
            cf[n * 400 + j] = mid_states[n * 400 + j] + u;
        }
        __syncthreads();
        if (t == 0) __hip_atomic_fetch_add(&ctrs[27], 1, __ATOMIC_ACQ_REL, __HIP_MEMORY_SCOPE_AGENT);
    }
}

__device__ void dev_rootagg(int chunk, const float* __restrict__ W, const float* __restrict__ cf,
                            float* __restrict__ partial_r, int* __restrict__ ctrs) {
    spin_wait(&ctrs[27], 27);
    __shared__ float c_l[100];
    int t = threadIdx.x;
    if (t < 100) c_l[t] = cf[chunk * 100 + t];
    __syncthreads();
    if (t < 200) {
        int rp = t / 100, j4 = t % 100;
        const v4f* Wr = (const v4f*)W + (size_t)(chunk * 100) * 100;
        v4f acc = (v4f)(0.0f);
        #pragma unroll 10
        for (int rr = 0; rr < 50; ++rr) {
            int r = 2 * rr + rp;
            v4f w = __builtin_nontemporal_load(&Wr[(size_t)r * 100 + j4]);
            acc += c_l[r] * w;
        }
        ((v4f*)(partial_r + (size_t)(chunk * 2 + rp) * 400))[j4] = acc;
    }
    __syncthreads();
    if (t == 0) __hip_atomic_fetch_add(&ctrs[28], 1, __ATOMIC_ACQ_REL, __HIP_MEMORY_SCOPE_AGENT);
}

__device__ void dev_rootup(int qd, const float* __restrict__ partial_r, const float* __restrict__ agg_b,
                           const float* __restrict__ root_state,
                           const float* __restrict__ W1, const float* __restrict__ b1,
                           const float* __restrict__ W2, const float* __restrict__ b2,
                           float* __restrict__ out, float* __restrict__ hpr, int* __restrict__ ctrs) {
    spin_wait(&ctrs[28], 108);
    __shared__ float combq[200];
    __shared__ float hp4[4][64];
    __shared__ float hid[64];
    __shared__ int flag;
    int t = threadIdx.x;
    if (qd < 2) {
        if (t < 200) combq[t] = root_state[qd * 200 + t];
    } else {
        int j0 = (qd - 2) * 200;
        if (t < 200) {
            float a = agg_b[j0 + t];
            const float* pp = partial_r + j0 + t;
            #pragma unroll 12
            for (int s = 0; s < 216; ++s) a += pp[s * 400];
            combq[t] = a;
        }
    }
    __syncthreads();
    {
        int h = t & 63, g = t >> 6;
        const float* w1 = W1 + (size_t)(qd * 200) * 64;
        float hs = 0.0f;
        #pragma unroll 5
        for (int i = g * 50; i < g * 50 + 50; ++i) hs += combq[i] * w1[i * 64 + h];
        hp4[g][h] = hs;
    }
    __syncthreads();
    if (t < 64) hpr[qd * 64 + t] = hp4[0][t] + hp4[1][t] + hp4[2][t] + hp4[3][t];
    __syncthreads();
    if (t == 0) {
        int old = __hip_atomic_fetch_add(&ctrs[29], 1, __ATOMIC_ACQ_REL, __HIP_MEMORY_SCOPE_AGENT);
        flag = (old == 3);
    }
    __syncthreads();
    if (flag) {
        if (t < 64) {
            float hs = b1[t];
            #pragma unroll
            for (int pq = 0; pq < 4; ++pq) hs += hpr[pq * 64 + t];
            hid[t] = fmaxf(hs, 0.0f);
        }
        __syncthreads();
        for (int j = t; j < 400; j += 256) {
            float u = b2[j];
            #pragma unroll 8
            for (int k = 0; k < 64; ++k) u += hid[k] * W2[k * 400 + j];
            out[j] = root_state[j] + u;
        }
    }
}

__global__ __launch_bounds__(256) void k_tail(
    const float* __restrict__ qkv, const float* __restrict__ mha_out_W,
    const float* __restrict__ mha_out_b, float* __restrict__ out_att,
    const float* __restrict__ ent_scaled, const float* __restrict__ q_real,
    const float* __restrict__ q_imag, const float* __restrict__ meas_W,
    const float* __restrict__ meas_b, float* __restrict__ out_meas,
    const float* __restrict__ mid_partial, const float* __restrict__ mid_agg_b,
    const float* __restrict__ mid_states,
    const float* __restrict__ mid_up_W1, const float* __restrict__ mid_up_b1,
    const float* __restrict__ mid_up_W2, const float* __restrict__ mid_up_b2,
    float* __restrict__ cf,
    const float* __restrict__ root_agg_W, const float* __restrict__ root_agg_b,
    const float* __restrict__ root_state,
    const float* __restrict__ root_up_W1, const float* __restrict__ root_up_b1,
    const float* __restrict__ root_up_W2, const float* __restrict__ root_up_b2,
    float* __restrict__ out_root,
    float* __restrict__ partial_r, float* __restrict__ hpm, float* __restrict__ hpr,
    int* __restrict__ ctrs) {
    int blk = blockIdx.x;
    if (blk < 27)        dev_attnproj(blk, qkv, mha_out_W, mha_out_b, out_att);
    else if (blk < 61)   dev_measured(blk - 27, ent_scaled, q_real, q_imag, meas_W, meas_b, out_meas);
    else if (blk < 169)  dev_mid_up(blk - 61, mid_partial, mid_agg_b, mid_states,
                                    mid_up_W1, mid_up_b1, mid_up_W2, mid_up_b2, cf, hpm, ctrs);
    else if (blk < 277)  dev_rootagg(blk - 169, root_agg_W, cf, partial_r, ctrs);
    else                 dev_rootup(blk - 277, partial_r, root_agg_b, root_state,
                                    root_up_W1, root_up_b1, root_up_W2, root_up_b2,
                                    out_root, hpr, ctrs);
}

extern "C" void kernel_launch(void* const* d_in, const int* in_sizes, int n_in,
                              void* d_out, int out_size, void* d_ws, size_t ws_size,
                              hipStream_t stream) {
    const float* node       = (const float*)d_in[0];
    const float* hist       = (const float*)d_in[1];
    const float* gW         = (const float*)d_in[2];
    const float* gb         = (const float*)d_in[3];
    const float* mha_in_W   = (const float*)d_in[4];
    const float* mha_in_b   = (const float*)d_in[5];
    const float* mha_out_W  = (const float*)d_in[6];
    const float* mha_out_b  = (const float*)d_in[7];
    const float* q_real     = (const float*)d_in[8];
    const float* q_imag     = (const float*)d_in[9];
    const float* ent_W1     = (const float*)d_in[10];
    const float* ent_b1     = (const float*)d_in[11];
    const float* ent_W2     = (const float*)d_in[12];
    const float* ent_b2     = (const float*)d_in[13];
    const float* meas_W     = (const float*)d_in[14];
    const float* meas_b     = (const float*)d_in[15];
    const float* leaf       = (const float*)d_in[16];
    const float* mid_states = (const float*)d_in[17];
    const float* root_state = (const float*)d_in[18];
    const float* mid_agg_W  = (const float*)d_in[19];
    const float* mid_agg_b  = (const float*)d_in[20];
    const float* root_agg_W = (const float*)d_in[21];
    const float* root_agg_b = (const float*)d_in[22];
    const float* mid_up_W1  = (const float*)d_in[23];
    const float* mid_up_b1  = (const float*)d_in[24];
    const float* mid_up_W2  = (const float*)d_in[25];
    const float* mid_up_b2  = (const float*)d_in[26];
    const float* root_up_W1 = (const float*)d_in[27];
    const float* root_up_b1 = (const float*)d_in[28];
    const float* root_up_W2 = (const float*)d_in[29];
    const float* root_up_b2 = (const float*)d_in[30];

    float* ws          = (float*)d_ws;
    float* qkv         = ws + WS_QKV;
    float* ent_scaled  = ws + WS_ENT;
    float* mid_partial = ws + WS_MIDP;
    float* cf          = ws + WS_CF;
    float* partial_r   = ws + WS_ROOTP;
    float* hpm         = ws + WS_HPM;
    float* hpr         = ws + WS_HPR;
    int*   ctrs        = (int*)(ws + WS_CTR);

    float* out        = (float*)d_out;
    float* out_causal = out;            // 729
    float* out_att    = out + 729;      // 8640
    float* out_meas   = out + 9369;     // 8640
    float* out_root   = out + 18009;    // 400

    hipLaunchKernelGGL(k_stage1, dim3(AGG_BLKS + 105 + 176), dim3(256), 0, stream,
                       mid_agg_W, leaf, node, hist, gW, gb, mha_in_W, mha_in_b,
                       q_real, ent_W1, ent_b1, ent_W2, ent_b2,
                       mid_partial, out_causal, qkv, ent_scaled, ctrs);

    hipLaunchKernelGGL(k_tail, dim3(281), dim3(256), 0, stream,
                       qkv, mha_out_W, mha_out_b, out_att,
                       ent_scaled, q_real, q_imag, meas_W, meas_b, out_meas,
                       mid_partial, mid_agg_b, mid_states,
                       mid_up_W1, mid_up_b1, mid_up_W2, mid_up_b2, cf,
                       root_agg_W, root_agg_b, root_state,
                       root_up_W1, root_up_b1, root_up_W2, root_up_b2, out_root,
                       partial_r, hpm, hpr, ctrs);
}

// Round 7
// 141.773 us; speedup vs baseline: 1.1827x; 1.1827x over previous
//
#include <hip/hip_runtime.h>
#include <math.h>

typedef float v4f __attribute__((ext_vector_type(4)));

// ---------------- geometry ----------------
#define SD 64
#define CC 64
#define EE 320
#define NS 27
#define NPAIR 351

#define NCHUNK 54
#define AGG_BLKS (27 * NCHUNK)   // 1458

// ws layout (floats)
#define WS_QKV   0                       // 27*960 = 25920
#define WS_ENT   25920                   // 351*64 = 22464 -> 48384
#define WS_MIDP  48384                   // 1458*2*400 = 1166400 -> 1214784
#define WS_CF    1214784                 // 10800 -> 1225584
#define WS_ROOTP 1225584                 // 108*400 = 43200 -> 1268784
#define WS_HPM   1268784                 // 27*4*64 = 6912 -> 1275696
#define WS_HPR   1275696                 // 256 -> 1275952
#define WS_CTR   1275968                 // 32 ints
// ctr indices: [0..26] per-node mid quarters, [30] root quarters

// ================= K1 (256 threads): mid_agg | granger | qkv | ent =================

__device__ void dev_mid_agg(int blk, const float* __restrict__ W,
                            const float* __restrict__ leaf, float* __restrict__ partial) {
    __shared__ float c_l[200];
    int n = blk / NCHUNK, chunk = blk % NCHUNK;
    int t = threadIdx.x;
    if (t < 200) c_l[t] = leaf[n * 10800 + chunk * 200 + t];
    __syncthreads();
    if (t < 200) {
        int rp = t / 100, j4 = t % 100;
        const v4f* Wr = (const v4f*)(W + (size_t)(n * 10800 + chunk * 200) * 400);
        v4f acc = (v4f)(0.0f);
        #pragma unroll 16
        for (int rr = 0; rr < 100; ++rr) {
            int r = 2 * rr + rp;
            v4f w = __builtin_nontemporal_load(&Wr[(size_t)r * 100 + j4]);
            acc += c_l[r] * w;
        }
        ((v4f*)(partial + (size_t)(blk * 2 + rp) * 400))[j4] = acc;
    }
}

__device__ void dev_granger(int blk, const float* __restrict__ x, const float* __restrict__ h,
                            const float* __restrict__ gW, const float* __restrict__ gb,
                            float* __restrict__ out) {
    int idx = blk * 256 + threadIdx.x;
    if (idx >= NS * NS) return;
    int i = idx / NS, j = idx % NS;
    const float* hr = h + j * 320;
    const float* xr = x + i * 320;
    float acc = gb[0];
    for (int k = 0; k < 320; ++k) acc += hr[k] * gW[k] + xr[k] * gW[320 + k];
    float sig = 1.0f / (1.0f + expf(-acc));
    out[idx] = (i == j) ? 0.0f : sig;
}

__device__ void dev_qkv(int blk, const float* __restrict__ x, const float* __restrict__ W,
                        const float* __restrict__ b, float* __restrict__ qkv) {
    int idx = blk * 256 + threadIdx.x;
    if (idx >= NS * 960) return;
    int i = idx / 960, c = idx % 960;
    const float4* xr = (const float4*)(x + i * 320);
    const float4* wr = (const float4*)(W + (size_t)c * 320);
    float acc = b[c];
    #pragma unroll 8
    for (int k = 0; k < 80; ++k) {
        float4 a = xr[k], w = wr[k];
        acc += a.x * w.x + a.y * w.y + a.z * w.z + a.w * w.w;
    }
    qkv[idx] = acc;
}

__device__ void dev_ent(int blk, const float* __restrict__ q_real,
                        const float* __restrict__ W1, const float* __restrict__ b1,
                        const float* __restrict__ W2, const float* __restrict__ b2,
                        float* __restrict__ ent_scaled) {
    __shared__ float comb[2][128];
    __shared__ float hid[2][64];
    int t = threadIdx.x;
    int sub = t >> 7, lt = t & 127;
    int p = blk * 2 + sub;
    bool pv = (p < NPAIR);
    bool valid = pv && (lt < 64);
    int i = 0, jj = 0;
    if (pv) {
        int rem = p;
        while (rem >= 26 - i) { rem -= 26 - i; ++i; }
        jj = i + 1 + rem;
    }
    float qa = 0.f, qb = 0.f;
    if (valid) { qa = q_real[i * CC + lt]; qb = q_real[jj * CC + lt]; }
    float sa = qa, sb = qb;
    #pragma unroll
    for (int off = 32; off; off >>= 1) { sa += __shfl_xor(sa, off); sb += __shfl_xor(sb, off); }
    float coupling = expf(-fabsf(sa - sb) / (500.0f + 1e-6f));
    if (valid) { comb[sub][lt] = qa; comb[sub][64 + lt] = qb; }
    __syncthreads();
    if (valid) {
        float hs = b1[lt];
        for (int ii = 0; ii < 128; ++ii) hs += comb[sub][ii] * W1[ii * 64 + lt];
        hid[sub][lt] = fmaxf(hs, 0.0f);
    }
    __syncthreads();
    if (valid) {
        float e = b2[lt];
        for (int k = 0; k < 64; ++k) e += hid[sub][k] * W2[k * 64 + lt];
        ent_scaled[p * 64 + lt] = e * coupling;
    }
}

__global__ __launch_bounds__(256) void k_stage1(
    const float* __restrict__ mid_agg_W, const float* __restrict__ leaf,
    const float* __restrict__ node, const float* __restrict__ hist,
    const float* __restrict__ gW, const float* __restrict__ gb,
    const float* __restrict__ mha_in_W, const float* __restrict__ mha_in_b,
    const float* __restrict__ q_real,
    const float* __restrict__ ent_W1, const float* __restrict__ ent_b1,
    const float* __restrict__ ent_W2, const float* __restrict__ ent_b2,
    float* __restrict__ mid_partial, float* __restrict__ out_causal,
    float* __restrict__ qkv, float* __restrict__ ent_scaled,
    int* __restrict__ ctrs) {
    int blk = blockIdx.x;
    if (blk == 0 && threadIdx.x >= 224) ctrs[threadIdx.x - 224] = 0;
    if (blk < AGG_BLKS)            dev_mid_agg(blk, mid_agg_W, leaf, mid_partial);
    else if (blk < AGG_BLKS + 3)   dev_granger(blk - AGG_BLKS, node, hist, gW, gb, out_causal);
    else if (blk < AGG_BLKS + 105) dev_qkv(blk - AGG_BLKS - 3, node, mha_in_W, mha_in_b, qkv);
    else                           dev_ent(blk - AGG_BLKS - 105, q_real, ent_W1, ent_b1, ent_W2, ent_b2, ent_scaled);
}

// ================= K2 (512 threads): attn | avg | mid_up quarters =================
// blocks: [0,108) attn, 108 avg, [109,217) mid_up quarters (27 nodes x 4)

__device__ void dev_attn(int blk, const float* __restrict__ qkv, float* __restrict__ o) {
    int h = blk / NS, q = blk % NS;
    int t = threadIdx.x;
    __shared__ float sc[NS];
    __shared__ float at[NS];
    if (t < NS) {
        const float* qrow = qkv + q * 960 + h * 80;
        const float* krow = qkv + t * 960 + EE + h * 80;
        float s = 0.0f;
        for (int d = 0; d < 80; ++d) s += qrow[d] * krow[d];
        sc[t] = s * 0.1118033988749895f;
    }
    __syncthreads();
    if (t < NS) {
        float m = -1e30f;
        for (int s2 = 0; s2 < NS; ++s2) m = fmaxf(m, sc[s2]);
        float sum = 0.0f;
        for (int s2 = 0; s2 < NS; ++s2) sum += expf(sc[s2] - m);
        at[t] = expf(sc[t] - m) / sum;
    }
    __syncthreads();
    if (t < 80) {
        float acc = 0.0f;
        for (int s2 = 0; s2 < NS; ++s2) acc += at[s2] * qkv[s2 * 960 + 2 * EE + h * 80 + t];
        o[q * EE + h * 80 + t] = acc;
    }
}

__device__ void dev_avg(const float* __restrict__ ent_scaled, float* __restrict__ avg) {
    __shared__ float aacc[8][64];
    int t = threadIdx.x;
    int col = t & 63, grp = t >> 6;
    float s = 0.0f;
    for (int p = grp; p < NPAIR; p += 8) s += ent_scaled[p * 64 + col];
    aacc[grp][col] = s;
    __syncthreads();
    if (t < 64) {
        float a = 0.0f;
        #pragma unroll
        for (int g = 0; g < 8; ++g) a += aacc[g][t];
        avg[t] = a / (float)NPAIR;
    }
}

__device__ void dev_mid_up(int rel, const float* __restrict__ partial, const float* __restrict__ agg_b,
                           const float* __restrict__ mid_states,
                           const float* __restrict__ W1, const float* __restrict__ b1,
                           const float* __restrict__ W2, const float* __restrict__ b2,
                           float* __restrict__ cf, float* __restrict__ hpm, int* __restrict__ ctrs) {
    int n = rel >> 2, p = rel & 3;
    __shared__ float combq[200];
    __shared__ float hp8[8][64];
    __shared__ float hid[64];
    __shared__ int flag;
    int t = threadIdx.x;
    if (p < 2) {
        if (t < 200) combq[t] = mid_states[n * 400 + p * 200 + t];
    } else {
        int j0 = (p - 2) * 200;
        if (t < 200) {
            float a = agg_b[n * 400 + j0 + t];
            const float* pp = partial + (size_t)(n * 108) * 400 + j0 + t;
            #pragma unroll 12
            for (int s = 0; s < 108; ++s) a += pp[s * 400];
            combq[t] = a;
        }
    }
    __syncthreads();
    {
        int h = t & 63, g = t >> 6;   // 8 groups of 25 rows
        const float* w1 = W1 + (size_t)n * 51200 + (size_t)(p * 200) * 64;
        float hs = 0.0f;
        #pragma unroll 5
        for (int i = g * 25; i < g * 25 + 25; ++i) hs += combq[i] * w1[i * 64 + h];
        hp8[g][h] = hs;
    }
    __syncthreads();
    if (t < 64) {
        float hs = 0.0f;
        #pragma unroll
        for (int g = 0; g < 8; ++g) hs += hp8[g][t];
        hpm[(n * 4 + p) * 64 + t] = hs;
    }
    __syncthreads();
    if (t == 0) {
        int old = __hip_atomic_fetch_add(&ctrs[n], 1, __ATOMIC_ACQ_REL, __HIP_MEMORY_SCOPE_AGENT);
        flag = (old == 3);
    }
    __syncthreads();
    if (flag) {
        if (t < 64) {
            float hs = b1[n * 64 + t];
            #pragma unroll
            for (int pq = 0; pq < 4; ++pq) hs += hpm[(n * 4 + pq) * 64 + t];
            hid[t] = fmaxf(hs, 0.0f);
        }
        __syncthreads();
        const float* w2 = W2 + (size_t)n * 25600;
        if (t < 400) {
            float u = b2[n * 400 + t];
            #pragma unroll 8
            for (int k = 0; k < 64; ++k) u += hid[k] * w2[k * 400 + t];
            cf[n * 400 + t] = mid_states[n * 400 + t] + u;
        }
    }
}

__global__ __launch_bounds__(512) void k_stage2(
    const float* __restrict__ qkv, float* __restrict__ o,
    const float* __restrict__ ent_scaled, float* __restrict__ avg,
    const float* __restrict__ mid_partial, const float* __restrict__ mid_agg_b,
    const float* __restrict__ mid_states,
    const float* __restrict__ mid_up_W1, const float* __restrict__ mid_up_b1,
    const float* __restrict__ mid_up_W2, const float* __restrict__ mid_up_b2,
    float* __restrict__ cf, float* __restrict__ hpm, int* __restrict__ ctrs) {
    int blk = blockIdx.x;
    if (blk < 108)       dev_attn(blk, qkv, o);
    else if (blk == 108) dev_avg(ent_scaled, avg);
    else                 dev_mid_up(blk - 109, mid_partial, mid_agg_b, mid_states,
                                    mid_up_W1, mid_up_b1, mid_up_W2, mid_up_b2, cf, hpm, ctrs);
}

// ================= K3 (512 threads): proj | measured | root_agg =================
// blocks: [0,17) proj, [17,34) measured, [34,142) root_agg chunks (108 x 100 rows)

__device__ void dev_proj(int blk, const float* __restrict__ o, const float* __restrict__ W,
                         const float* __restrict__ b, float* __restrict__ outp) {
    int idx = blk * 512 + threadIdx.x;
    if (idx >= NS * EE) return;
    int i = idx / EE, c = idx % EE;
    const float4* orow = (const float4*)(o + i * EE);
    const float4* wr = (const float4*)(W + (size_t)c * EE);
    float acc = b[c];
    #pragma unroll 8
    for (int k = 0; k < 80; ++k) {
        float4 a = orow[k], w = wr[k];
        acc += a.x * w.x + a.y * w.y + a.z * w.z + a.w * w.w;
    }
    outp[idx] = 0.5f * acc;
}

__device__ void dev_measured(int blk, const float* __restrict__ q_real, const float* __restrict__ q_imag,
                             const float* __restrict__ avg, const float* __restrict__ W,
                             const float* __restrict__ b, float* __restrict__ out) {
    int idx = blk * 512 + threadIdx.x;
    if (idx >= NS * EE) return;
    int i = idx / EE, c = idx % EE;
    float acc = b[c];
    #pragma unroll 8
    for (int k = 0; k < 64; ++k) {
        float a = avg[k];
        acc += (q_real[i * 64 + k] + a) * W[k * EE + c];
        acc += (q_imag[i * 64 + k] + a) * W[(64 + k) * EE + c];
    }
    out[idx] = acc;
}

__device__ void dev_rootagg(int chunk, const float* __restrict__ W, const float* __restrict__ cf,
                            float* __restrict__ partial_r) {
    __shared__ float racc[5][400];
    int t = threadIdx.x;
    int rp = t / 100, j4 = t % 100;   // rp in {0..4}
    if (rp < 5) {
        const float* c = cf + chunk * 100;
        const v4f* Wr = (const v4f*)W + (size_t)(chunk * 100) * 100;
        v4f acc = (v4f)(0.0f);
        #pragma unroll
        for (int rr = 0; rr < 20; ++rr) {
            int r = 5 * rr + rp;
            float cv = c[r];
            v4f w = __builtin_nontemporal_load(&Wr[(size_t)r * 100 + j4]);
            acc += cv * w;
        }
        racc[rp][j4 * 4 + 0] = acc.x;
        racc[rp][j4 * 4 + 1] = acc.y;
        racc[rp][j4 * 4 + 2] = acc.z;
        racc[rp][j4 * 4 + 3] = acc.w;
    }
    __syncthreads();
    if (t < 400) {
        float a = 0.0f;
        #pragma unroll
        for (int g = 0; g < 5; ++g) a += racc[g][t];
        partial_r[chunk * 400 + t] = a;
    }
}

__global__ __launch_bounds__(512) void k_stage3(
    const float* __restrict__ o, const float* __restrict__ mha_out_W,
    const float* __restrict__ mha_out_b, float* __restrict__ out_att,
    const float* __restrict__ q_real, const float* __restrict__ q_imag,
    const float* __restrict__ avg, const float* __restrict__ meas_W,
    const float* __restrict__ meas_b, float* __restrict__ out_meas,
    const float* __restrict__ root_agg_W, const float* __restrict__ cf,
    float* __restrict__ partial_r) {
    int blk = blockIdx.x;
    if (blk < 17)       dev_proj(blk, o, mha_out_W, mha_out_b, out_att);
    else if (blk < 34)  dev_measured(blk - 17, q_real, q_imag, avg, meas_W, meas_b, out_meas);
    else                dev_rootagg(blk - 34, root_agg_W, cf, partial_r);
}

// ================= K4 (512 threads, 4 blocks): root quarters + last-arrival finish =================
__global__ __launch_bounds__(512) void k_root(
    const float* __restrict__ partial_r, const float* __restrict__ agg_b,
    const float* __restrict__ root_state,
    const float* __restrict__ W1, const float* __restrict__ b1,
    const float* __restrict__ W2, const float* __restrict__ b2,
    float* __restrict__ out, float* __restrict__ hpr, int* __restrict__ ctrs) {
    int qd = blockIdx.x;
    __shared__ float combq[200];
    __shared__ float hp8[8][64];
    __shared__ float hid[64];
    __shared__ int flag;
    int t = threadIdx.x;
    if (qd < 2) {
        if (t < 200) combq[t] = root_state[qd * 200 + t];
    } else {
        int j0 = (qd - 2) * 200;
        if (t < 200) {
            float a = agg_b[j0 + t];
            const float* pp = partial_r + j0 + t;
            #pragma unroll 12
            for (int s = 0; s < 108; ++s) a += pp[s * 400];
            combq[t] = a;
        }
    }
    __syncthreads();
    {
        int h = t & 63, g = t >> 6;
        const float* w1 = W1 + (size_t)(qd * 200) * 64;
        float hs = 0.0f;
        #pragma unroll 5
        for (int i = g * 25; i < g * 25 + 25; ++i) hs += combq[i] * w1[i * 64 + h];
        hp8[g][h] = hs;
    }
    __syncthreads();
    if (t < 64) {
        float hs = 0.0f;
        #pragma unroll
        for (int g = 0; g < 8; ++g) hs += hp8[g][t];
        hpr[qd * 64 + t] = hs;
    }
    __syncthreads();
    if (t == 0) {
        int old = __hip_atomic_fetch_add(&ctrs[30], 1, __ATOMIC_ACQ_REL, __HIP_MEMORY_SCOPE_AGENT);
        flag = (old == 3);
    }
    __syncthreads();
    if (flag) {
        if (t < 64) {
            float hs = b1[t];
            #pragma unroll
            for (int pq = 0; pq < 4; ++pq) hs += hpr[pq * 64 + t];
            hid[t] = fmaxf(hs, 0.0f);
        }
        __syncthreads();
        if (t < 400) {
            float u = b2[t];
            #pragma unroll 8
            for (int k = 0; k < 64; ++k) u += hid[k] * W2[k * 400 + t];
            out[t] = root_state[t] + u;
        }
    }
}

extern "C" void kernel_launch(void* const* d_in, const int* in_sizes, int n_in,
                              void* d_out, int out_size, void* d_ws, size_t ws_size,
                              hipStream_t stream) {
    const float* node       = (const float*)d_in[0];
    const float* hist       = (const float*)d_in[1];
    const float* gW         = (const float*)d_in[2];
    const float* gb         = (const float*)d_in[3];
    const float* mha_in_W   = (const float*)d_in[4];
    const float* mha_in_b   = (const float*)d_in[5];
    const float* mha_out_W  = (const float*)d_in[6];
    const float* mha_out_b  = (const float*)d_in[7];
    const float* q_real     = (const float*)d_in[8];
    const float* q_imag     = (const float*)d_in[9];
    const float* ent_W1     = (const float*)d_in[10];
    const float* ent_b1     = (const float*)d_in[11];
    const float* ent_W2     = (const float*)d_in[12];
    const float* ent_b2     = (const float*)d_in[13];
    const float* meas_W     = (const float*)d_in[14];
    const float* meas_b     = (const float*)d_in[15];
    const float* leaf       = (const float*)d_in[16];
    const float* mid_states = (const float*)d_in[17];
    const float* root_state = (const float*)d_in[18];
    const float* mid_agg_W  = (const float*)d_in[19];
    const float* mid_agg_b  = (const float*)d_in[20];
    const float* root_agg_W = (const float*)d_in[21];
    const float* root_agg_b = (const float*)d_in[22];
    const float* mid_up_W1  = (const float*)d_in[23];
    const float* mid_up_b1  = (const float*)d_in[24];
    const float* mid_up_W2  = (const float*)d_in[25];
    const float* mid_up_b2  = (const float*)d_in[26];
    const float* root_up_W1 = (const float*)d_in[27];
    const float* root_up_b1 = (const float*)d_in[28];
    const float* root_up_W2 = (const float*)d_in[29];
    const float* root_up_b2 = (const float*)d_in[30];

    float* ws          = (float*)d_ws;
    float* qkv         = ws + WS_QKV;
    float* ent_scaled  = ws + WS_ENT;
    float* mid_partial = ws + WS_MIDP;
    float* cf          = ws + WS_CF;
    float* partial_r   = ws + WS_ROOTP;
    float* hpm         = ws + WS_HPM;
    float* hpr         = ws + WS_HPR;
    int*   ctrs        = (int*)(ws + WS_CTR);

    // o reuses qkv's tail region? No: keep separate small buffer after ctrs
    float* o = ws + WS_CTR + 32;   // 27*320 = 8640 floats

    float* out        = (float*)d_out;
    float* out_causal = out;            // 729
    float* out_att    = out + 729;      // 8640
    float* out_meas   = out + 9369;     // 8640
    float* out_root   = out + 18009;    // 400

    float* avg = o + 8640;              // 64 floats

    hipLaunchKernelGGL(k_stage1, dim3(AGG_BLKS + 105 + 176), dim3(256), 0, stream,
                       mid_agg_W, leaf, node, hist, gW, gb, mha_in_W, mha_in_b,
                       q_real, ent_W1, ent_b1, ent_W2, ent_b2,
                       mid_partial, out_causal, qkv, ent_scaled, ctrs);

    hipLaunchKernelGGL(k_stage2, dim3(217), dim3(512), 0, stream,
                       qkv, o, ent_scaled, avg, mid_partial, mid_agg_b, mid_states,
                       mid_up_W1, mid_up_b1, mid_up_W2, mid_up_b2, cf, hpm, ctrs);

    hipLaunchKernelGGL(k_stage3, dim3(142), dim3(512), 0, stream,
                       o, mha_out_W, mha_out_b, out_att,
                       q_real, q_imag, avg, meas_W, meas_b, out_meas,
                       root_agg_W, cf, partial_r);

    hipLaunchKernelGGL(k_root, dim3(4), dim3(512), 0, stream,
                       partial_r, root_agg_b, root_state,
                       root_up_W1, root_up_b1, root_up_W2, root_up_b2, out_root, hpr, ctrs);
}